// Round 2
// baseline (2315.608 us; speedup 1.0000x reference)
//
#include <hip/hip_runtime.h>

#define Gn 128
#define Tn 512
#define Sn 24
#define SP 28   // padded LDS row stride (16B-aligned)
#define Mn 4
#define COVS_BASE (Gn * Tn * Mn)   // 262144

__device__ __forceinline__ float4 ld4(const float* p) {
    return *reinterpret_cast<const float4*>(p);
}
__device__ __forceinline__ void st4(float* p, float4 v) {
    *reinterpret_cast<float4*>(p) = v;
}
__device__ __forceinline__ float dot4(float4 a, float4 b) {
    return a.x*b.x + a.y*b.y + a.z*b.z + a.w*b.w;
}

struct Row24 { float4 v[6]; };

__device__ __forceinline__ Row24 loadRow(const float* p) {
    Row24 r;
#pragma unroll
    for (int i = 0; i < 6; ++i) r.v[i] = ld4(p + 4*i);
    return r;
}

__device__ __forceinline__ float dot24(const Row24& a, const float* b) {
    float4 b0 = ld4(b+0), b1 = ld4(b+4), b2 = ld4(b+8),
           b3 = ld4(b+12), b4 = ld4(b+16), b5 = ld4(b+20);
    float s0 = dot4(a.v[0], b0);
    float s1 = dot4(a.v[1], b1);
    float s2 = dot4(a.v[2], b2);
    float s3 = dot4(a.v[3], b3);
    float s4 = dot4(a.v[4], b4);
    float s5 = dot4(a.v[5], b5);
    return ((s0+s1)+(s2+s3))+(s4+s5);
}

__device__ __forceinline__ float dot24rr(const Row24& a, const Row24& b) {
    float s0 = dot4(a.v[0], b.v[0]);
    float s1 = dot4(a.v[1], b.v[1]);
    float s2 = dot4(a.v[2], b.v[2]);
    float s3 = dot4(a.v[3], b.v[3]);
    float s4 = dot4(a.v[4], b.v[4]);
    float s5 = dot4(a.v[5], b.v[5]);
    return ((s0+s1)+(s2+s3))+(s4+s5);
}

__device__ __forceinline__ float rlane(float v, int l) {
    return __int_as_float(__builtin_amdgcn_readlane(__float_as_int(v), l));
}

// Single-wave LDS RAW ordering: lockstep HW + lgkm wait. No s_barrier anywhere.
__device__ __forceinline__ void waveLds() {
    asm volatile("s_waitcnt lgkmcnt(0)" ::: "memory");
    __builtin_amdgcn_wave_barrier();
    asm volatile("" ::: "memory");
}

extern "C" __global__ void __launch_bounds__(64, 1)
kalman_kernel(const float* __restrict__ y_g, const float* __restrict__ F_g,
              const float* __restrict__ Q_g, const float* __restrict__ H_g,
              const float* __restrict__ R_g, const float* __restrict__ m0_g,
              const float* __restrict__ P0_g, float* __restrict__ out)
{
    const int g    = blockIdx.x;
    const int lane = threadIdx.x;     // 64 threads = one wave
    const int gT   = g * Tn;

    __shared__ __align__(16) float sP [Sn*SP];     // covariance (symmetric)
    __shared__ __align__(16) float sFP[Sn*SP];     // FP = F @ P
    __shared__ __align__(16) float sF [2][Sn*SP];
    __shared__ __align__(16) float sH [2][Mn*SP];
    __shared__ __align__(16) float sR [2][16];
    __shared__ __align__(16) float sy [2][4];
    __shared__ __align__(16) float sHP[Mn*SP];     // H@P rows (4 x 24)
    __shared__ __align__(16) float sW [Sn*4];      // W = FP@H^T (24 x 4, 16B rows)
    __shared__ __align__(16) float sMean[Sn];
    __shared__ __align__(16) float sFm [Sn];       // F @ m

    const float4* F4 = reinterpret_cast<const float4*>(F_g);
    const float4* H4 = reinterpret_cast<const float4*>(H_g);
    const float4* R4 = reinterpret_cast<const float4*>(R_g);
    const float4* y4 = reinterpret_cast<const float4*>(y_g);

    // staging: 173 float4 per step: F 144, H 24, R 4, y 1   (Q bypasses LDS)
    auto stage_load = [&](int v, int t) -> float4 {
        if (v < 144)      return F4[(size_t)(gT + t)*144 + v];
        else if (v < 168) return H4[(size_t)(gT + t)*24  + (v-144)];
        else if (v < 172) return R4[(size_t)(gT + t)*4   + (v-168)];
        else              return y4[gT + t];
    };
    auto stage_store = [&](int v, int bb, float4 val) {
        if (v < 144)      { int r = v/6, c = (v%6)*4;               st4(&sF[bb][r*SP+c], val); }
        else if (v < 168) { int v2 = v-144; int r = v2/6, c = (v2%6)*4; st4(&sH[bb][r*SP+c], val); }
        else if (v < 172) { st4(&sR[bb][(v-168)*4], val); }
        else              { st4(&sy[bb][0], val); }
    };

    // ---------------- prologue ----------------
    {
        int v0 = lane, v1 = lane + 64, v2 = lane + 128;
        st4(&sP[(v0/6)*SP + (v0%6)*4], ld4(&P0_g[(size_t)g*Sn*Sn + v0*4]));
        st4(&sP[(v1/6)*SP + (v1%6)*4], ld4(&P0_g[(size_t)g*Sn*Sn + v1*4]));
        if (lane < 16)
            st4(&sP[(v2/6)*SP + (v2%6)*4], ld4(&P0_g[(size_t)g*Sn*Sn + v2*4]));
        if (lane < 6)
            st4(&sMean[lane*4], ld4(&m0_g[(size_t)g*Sn + lane*4]));
        // stage t=0 synchronously
        stage_store(lane,      0, stage_load(lane,      0));
        stage_store(lane + 64, 0, stage_load(lane + 64, 0));
        if (lane < 45) stage_store(lane + 128, 0, stage_load(lane + 128, 0));
    }
    waveLds();

    // ---------------- hoisted per-lane indices ----------------
    const int ib = lane >> 3, jb = lane & 7;
    const int i0 = 3*ib, j0 = 3*jb;               // 3x3 output tile (FP, A, Pnew)
    const int aH = lane / 24, sH_ = lane % 24;    // HP out #1: o = lane
    const int o2 = 64 + lane;
    const int aH2 = o2 / 24, sH2 = o2 % 24;       // HP out #2 (lane<32)
    const int iW = lane >> 1, aW = (lane & 1)*2;  // W half-rows (lane<48)
    const bool muLane = (lane==1) | (lane==25) | (lane==49);   // mu for a = aH
    const bool needMean = (jb == 0) | muLane | (lane == 9);

    float4 pf0, pf1, pf2;

    for (int t = 0; t < Tn; ++t) {
        const int  b    = t & 1;
        const int  b1   = b ^ 1;
        const bool last = (t == Tn - 1);

        // prefetch-issue staging for t+1 (in flight across the whole step)
        if (!last) {
            pf0 = stage_load(lane,      t+1);
            pf1 = stage_load(lane + 64, t+1);
            if (lane < 45) pf2 = stage_load(lane + 128, t+1);
        }
        // Q for THIS step: direct global -> regs (consumed in S3, ~full step of slack)
        float qv[3][3];
        if (!last) {
            const float* Qp = Q_g + (size_t)(gT + t) * 576;
#pragma unroll
            for (int r = 0; r < 3; ++r)
#pragma unroll
                for (int c = 0; c < 3; ++c)
                    qv[r][c] = Qp[(i0+r)*24 + j0 + c];
        }

        // ================= S1: FP = F@P ; HP = H@P ; Fm ; mu/resid =================
        Row24 Fi0, Fi1, Fi2;
        float fp[3][3];
        if (!last) {
            Fi0 = loadRow(&sF[b][(i0+0)*SP]);
            Fi1 = loadRow(&sF[b][(i0+1)*SP]);
            Fi2 = loadRow(&sF[b][(i0+2)*SP]);
            Row24 Pj0 = loadRow(&sP[(j0+0)*SP]);   // P symmetric: col j == row j
            Row24 Pj1 = loadRow(&sP[(j0+1)*SP]);
            Row24 Pj2 = loadRow(&sP[(j0+2)*SP]);
            fp[0][0] = dot24rr(Fi0, Pj0); fp[0][1] = dot24rr(Fi0, Pj1); fp[0][2] = dot24rr(Fi0, Pj2);
            fp[1][0] = dot24rr(Fi1, Pj0); fp[1][1] = dot24rr(Fi1, Pj1); fp[1][2] = dot24rr(Fi1, Pj2);
            fp[2][0] = dot24rr(Fi2, Pj0); fp[2][1] = dot24rr(Fi2, Pj1); fp[2][2] = dot24rr(Fi2, Pj2);
        }
        // HP (96 outs: o=lane, and o=64+lane for lane<32)
        Row24 h1 = loadRow(&sH[b][aH*SP]);
        float hp1 = dot24(h1, &sP[sH_*SP]);
        Row24 h2; float hp2 = 0.f;
        if (lane < 32) {
            h2 = loadRow(&sH[b][aH2*SP]);
            hp2 = dot24(h2, &sP[sH2*SP]);
        }
        // mean row for Fm / mu
        Row24 mr;
        if (needMean) mr = loadRow(&sMean[0]);
        float fmv0, fmv1, fmv2;
        if (jb == 0 && !last) {
            fmv0 = dot24rr(Fi0, mr);
            fmv1 = dot24rr(Fi1, mr);
            fmv2 = dot24rr(Fi2, mr);
        }
        float residv = 0.f;
        if (muLane) {
            float mu = dot24rr(h1, mr);
            out[(size_t)(gT + t)*4 + aH] = mu;           // means output, a = 0,1,2
            residv = sy[b][aH] - mu;
        } else if (lane == 9) {                          // second H row of lane 9 is row 3
            float mu = dot24rr(h2, mr);
            out[(size_t)(gT + t)*4 + 3] = mu;
            residv = sy[b][3] - mu;
        }
        // LDS writes
        if (!last) {
#pragma unroll
            for (int r = 0; r < 3; ++r)
#pragma unroll
                for (int c = 0; c < 3; ++c)
                    sFP[(i0+r)*SP + j0 + c] = fp[r][c];
            if (jb == 0) { sFm[i0+0] = fmv0; sFm[i0+1] = fmv1; sFm[i0+2] = fmv2; }
        }
        sHP[aH*SP + sH_] = hp1;
        if (lane < 32) sHP[aH2*SP + sH2] = hp2;
        waveLds();   // #1

        // ================= S2: Sig(+covs) ; A = FP@F^T ; W = FP@H^T ; Inv =================
        float sigv = 0.f;
        if (lane >= 48) {
            int q = lane - 48;
            int a = q >> 2, c = q & 3;
            Row24 hpr = loadRow(&sHP[a*SP]);
            sigv = dot24(hpr, &sH[b][c*SP]) + sR[b][q];
            out[COVS_BASE + (size_t)(gT + t)*16 + q] = sigv;   // covs output
        }
        if (last) return;

        float acc[3][3];
        {
            Row24 FPi0 = loadRow(&sFP[(i0+0)*SP]);
            Row24 FPi1 = loadRow(&sFP[(i0+1)*SP]);
            Row24 FPi2 = loadRow(&sFP[(i0+2)*SP]);
            Row24 Fj0  = loadRow(&sF[b][(j0+0)*SP]);
            Row24 Fj1  = loadRow(&sF[b][(j0+1)*SP]);
            Row24 Fj2  = loadRow(&sF[b][(j0+2)*SP]);
            acc[0][0] = dot24rr(FPi0, Fj0); acc[0][1] = dot24rr(FPi0, Fj1); acc[0][2] = dot24rr(FPi0, Fj2);
            acc[1][0] = dot24rr(FPi1, Fj0); acc[1][1] = dot24rr(FPi1, Fj1); acc[1][2] = dot24rr(FPi1, Fj2);
            acc[2][0] = dot24rr(FPi2, Fj0); acc[2][1] = dot24rr(FPi2, Fj1); acc[2][2] = dot24rr(FPi2, Fj2);
        }
        if (lane < 48) {   // W: 96 outs, 2 per lane
            Row24 fpw = loadRow(&sFP[iW*SP]);
            sW[iW*4 + aW]     = dot24(fpw, &sH[b][aW*SP]);
            sW[iW*4 + aW + 1] = dot24(fpw, &sH[b][(aW+1)*SP]);
        }
        // Sig -> uniform registers via readlane; 4x4 inverse computed uniformly (no LDS)
        float s00 = rlane(sigv,48), s01 = rlane(sigv,49), s02 = rlane(sigv,50), s03 = rlane(sigv,51);
        float s10 = rlane(sigv,52), s11 = rlane(sigv,53), s12 = rlane(sigv,54), s13 = rlane(sigv,55);
        float s20 = rlane(sigv,56), s21 = rlane(sigv,57), s22 = rlane(sigv,58), s23 = rlane(sigv,59);
        float s30 = rlane(sigv,60), s31 = rlane(sigv,61), s32 = rlane(sigv,62), s33 = rlane(sigv,63);
        float p0 = s00*s11 - s01*s10;
        float p1 = s00*s12 - s02*s10;
        float p2 = s00*s13 - s03*s10;
        float p3 = s01*s12 - s02*s11;
        float p4 = s01*s13 - s03*s11;
        float p5 = s02*s13 - s03*s12;
        float q0 = s20*s31 - s21*s30;
        float q1 = s20*s32 - s22*s30;
        float q2 = s20*s33 - s23*s30;
        float q3 = s21*s32 - s22*s31;
        float q4 = s21*s33 - s23*s31;
        float q5 = s22*s33 - s23*s32;
        float det = p0*q5 - p1*q4 + p2*q3 + p3*q2 - p4*q1 + p5*q0;
        float rd  = 1.0f / det;
        float4 invr0 = make_float4(( s11*q5 - s12*q4 + s13*q3)*rd,
                                   (-s01*q5 + s02*q4 - s03*q3)*rd,
                                   ( s31*p5 - s32*p4 + s33*p3)*rd,
                                   (-s21*p5 + s22*p4 - s23*p3)*rd);
        float4 invr1 = make_float4((-s10*q5 + s12*q2 - s13*q1)*rd,
                                   ( s00*q5 - s02*q2 + s03*q1)*rd,
                                   (-s30*p5 + s32*p2 - s33*p1)*rd,
                                   ( s20*p5 - s22*p2 + s23*p1)*rd);
        float4 invr2 = make_float4(( s10*q4 - s11*q2 + s13*q0)*rd,
                                   (-s00*q4 + s01*q2 - s03*q0)*rd,
                                   ( s30*p4 - s31*p2 + s33*p0)*rd,
                                   (-s20*p4 + s21*p2 - s23*p0)*rd);
        float4 invr3 = make_float4((-s10*q3 + s11*q1 - s12*q0)*rd,
                                   ( s00*q3 - s01*q1 + s02*q0)*rd,
                                   (-s30*p3 + s31*p1 - s32*p0)*rd,
                                   ( s20*p3 - s21*p1 + s22*p0)*rd);
        waveLds();   // #2  (covers sW writes)

        // ================= S3: P = A + Q - (W Inv)W^T ; m_new ; land staging =================
        {
            float4 wi0 = ld4(&sW[(i0+0)*4]);
            float4 wi1 = ld4(&sW[(i0+1)*4]);
            float4 wi2 = ld4(&sW[(i0+2)*4]);
            float4 wj0 = ld4(&sW[(j0+0)*4]);
            float4 wj1 = ld4(&sW[(j0+1)*4]);
            float4 wj2 = ld4(&sW[(j0+2)*4]);
            float4 X0 = make_float4(dot4(wi0,invr0), dot4(wi0,invr1), dot4(wi0,invr2), dot4(wi0,invr3));
            float4 X1 = make_float4(dot4(wi1,invr0), dot4(wi1,invr1), dot4(wi1,invr2), dot4(wi1,invr3));
            float4 X2 = make_float4(dot4(wi2,invr0), dot4(wi2,invr1), dot4(wi2,invr2), dot4(wi2,invr3));
            sP[(i0+0)*SP + j0+0] = acc[0][0] + qv[0][0] - dot4(X0, wj0);
            sP[(i0+0)*SP + j0+1] = acc[0][1] + qv[0][1] - dot4(X0, wj1);
            sP[(i0+0)*SP + j0+2] = acc[0][2] + qv[0][2] - dot4(X0, wj2);
            sP[(i0+1)*SP + j0+0] = acc[1][0] + qv[1][0] - dot4(X1, wj0);
            sP[(i0+1)*SP + j0+1] = acc[1][1] + qv[1][1] - dot4(X1, wj1);
            sP[(i0+1)*SP + j0+2] = acc[1][2] + qv[1][2] - dot4(X1, wj2);
            sP[(i0+2)*SP + j0+0] = acc[2][0] + qv[2][0] - dot4(X2, wj0);
            sP[(i0+2)*SP + j0+1] = acc[2][1] + qv[2][1] - dot4(X2, wj1);
            sP[(i0+2)*SP + j0+2] = acc[2][2] + qv[2][2] - dot4(X2, wj2);
        }
        if (lane < 24) {   // m_new = Fm + (W Inv) resid
            float4 ws = ld4(&sW[lane*4]);
            float4 Xs = make_float4(dot4(ws,invr0), dot4(ws,invr1), dot4(ws,invr2), dot4(ws,invr3));
            float4 rs = make_float4(rlane(residv,1), rlane(residv,25), rlane(residv,49), rlane(residv,9));
            sMean[lane] = sFm[lane] + dot4(Xs, rs);
        }
        // land the t+1 staging prefetch into the other buffer
        stage_store(lane,      b1, pf0);
        stage_store(lane + 64, b1, pf1);
        if (lane < 45) stage_store(lane + 128, b1, pf2);
        waveLds();   // #3
    }
}

extern "C" void kernel_launch(void* const* d_in, const int* in_sizes, int n_in,
                              void* d_out, int out_size, void* d_ws, size_t ws_size,
                              hipStream_t stream) {
    kalman_kernel<<<Gn, 64, 0, stream>>>(
        (const float*)d_in[0], (const float*)d_in[1], (const float*)d_in[2],
        (const float*)d_in[3], (const float*)d_in[4], (const float*)d_in[5],
        (const float*)d_in[6], (float*)d_out);
}